// Round 4
// baseline (455.747 us; speedup 1.0000x reference)
//
#include <hip/hip_runtime.h>
#include <stdint.h>

#define B_ 4
#define S_ 2048
#define HID_ 1024
#define NH_ 16
#define HD_ 64

typedef __bf16 bf16x8 __attribute__((ext_vector_type(8)));
typedef __bf16 bf16x4 __attribute__((ext_vector_type(4)));
typedef float f32x4 __attribute__((ext_vector_type(4)));

__device__ inline void gload_lds16(const void* g, void* l) {
  __builtin_amdgcn_global_load_lds((const __attribute__((address_space(1))) unsigned int*)g,
                                   (__attribute__((address_space(3))) unsigned int*)l, 16, 0, 0);
}

__device__ inline f32x4 fmax4(f32x4 a, f32x4 b) {
  f32x4 r;
  r[0] = fmaxf(a[0], b[0]); r[1] = fmaxf(a[1], b[1]);
  r[2] = fmaxf(a[2], b[2]); r[3] = fmaxf(a[3], b[3]);
  return r;
}

// ---------------- fp32 -> bf16 conversion ----------------
__global__ __launch_bounds__(256) void cvt_bf16(const float* __restrict__ in, __bf16* __restrict__ out) {
  int i = (blockIdx.x * 256 + threadIdx.x) * 4;
  f32x4 v = *(const f32x4*)(in + i);
  bf16x4 o;
  o[0] = (__bf16)v[0]; o[1] = (__bf16)v[1]; o[2] = (__bf16)v[2]; o[3] = (__bf16)v[3];
  *(bf16x4*)(out + i) = o;
}

// ---------------- GEMM: C[M,N] = A[M,K]*Bt[N,K]^T (+bias) with fused epilogues --------
// MODE 1: float out (no bias)          -> Cf[m*N+n]
// MODE 2: bias + qknorm, bf16 out      -> Cb[m*1024+n]          (q projection)
// MODE 3: kv: n<1024 bias+qknorm -> Cb (k); n>=1024 bias -> vt[B,H,D,S] transposed (v)
template <int MODE>
__global__ __launch_bounds__(256) void gemm_bt(const __bf16* __restrict__ A,
                                               const __bf16* __restrict__ Bt,
                                               const float* __restrict__ bias,
                                               const float* __restrict__ gamma,
                                               __bf16* __restrict__ Cb,
                                               float* __restrict__ Cf,
                                               __bf16* __restrict__ vt,
                                               int M, int N, int K) {
  const int n0 = blockIdx.x * 128;
  const int m0 = blockIdx.y * 128;
  const int tid  = threadIdx.x;
  const int wave = tid >> 6, lane = tid & 63;
  const int wm = wave >> 1, wn = wave & 1;
  const int lrow = lane & 15, lgrp = lane >> 4;

  __shared__ __bf16 sA[128][64];
  __shared__ __bf16 sB[128][64];

  f32x4 acc[4][4];
#pragma unroll
  for (int i = 0; i < 4; i++)
#pragma unroll
    for (int j = 0; j < 4; j++) acc[i][j] = f32x4{0.f, 0.f, 0.f, 0.f};

  for (int k0 = 0; k0 < K; k0 += 64) {
    __syncthreads();
#pragma unroll
    for (int c = 0; c < 4; c++) {
      const int row = wave * 32 + c * 8;
      const __bf16* ga = A + (size_t)(m0 + row + (lane >> 3)) * K + k0 + (lane & 7) * 8;
      gload_lds16(ga, &sA[row][0]);
      const __bf16* gb = Bt + (size_t)(n0 + row + (lane >> 3)) * K + k0 + (lane & 7) * 8;
      gload_lds16(gb, &sB[row][0]);
    }
    __syncthreads();
#pragma unroll
    for (int kk = 0; kk < 2; kk++) {
      bf16x8 af[4], bfr[4];
#pragma unroll
      for (int i = 0; i < 4; i++) {
        af[i]  = *(const bf16x8*)(&sA[wm * 64 + i * 16 + lrow][kk * 32 + 8 * lgrp]);
        bfr[i] = *(const bf16x8*)(&sB[wn * 64 + i * 16 + lrow][kk * 32 + 8 * lgrp]);
      }
#pragma unroll
      for (int i = 0; i < 4; i++)
#pragma unroll
        for (int j = 0; j < 4; j++)
          acc[i][j] = __builtin_amdgcn_mfma_f32_16x16x32_bf16(af[i], bfr[j], acc[i][j], 0, 0, 0);
    }
  }

  // ---- epilogue ----
  if (MODE != 1) {
    float bv[4];
#pragma unroll
    for (int j = 0; j < 4; j++) bv[j] = bias[n0 + wn * 64 + j * 16 + lrow];
#pragma unroll
    for (int i = 0; i < 4; i++)
#pragma unroll
      for (int j = 0; j < 4; j++)
#pragma unroll
        for (int r = 0; r < 4; r++) acc[i][j][r] += bv[j];
  }

  const bool do_norm = (MODE == 2) || (MODE == 3 && n0 < 1024);
  if (do_norm) {
    float g[4];
#pragma unroll
    for (int j = 0; j < 4; j++) g[j] = gamma[(n0 + wn * 64 + j * 16 + lrow) & 1023];
#pragma unroll
    for (int i = 0; i < 4; i++) {
#pragma unroll
      for (int r = 0; r < 4; r++) {
        float ss = acc[i][0][r] * acc[i][0][r] + acc[i][1][r] * acc[i][1][r] +
                   acc[i][2][r] * acc[i][2][r] + acc[i][3][r] * acc[i][3][r];
#pragma unroll
        for (int off = 1; off < 16; off <<= 1) ss += __shfl_xor(ss, off, 64);
        const float inv = 8.f / fmaxf(sqrtf(ss), 1e-12f);
        const int m = m0 + wm * 64 + i * 16 + lgrp * 4 + r;
#pragma unroll
        for (int j = 0; j < 4; j++) {
          const int n = (n0 + wn * 64 + j * 16 + lrow) & 1023;
          Cb[(size_t)m * 1024 + n] = (__bf16)(acc[i][j][r] * inv * g[j]);
        }
      }
    }
  } else if (MODE == 3) {
    // v half: write transposed vt[b][h][d][s], packed 4 consecutive s per store
#pragma unroll
    for (int i = 0; i < 4; i++) {
#pragma unroll
      for (int j = 0; j < 4; j++) {
        const int nn = n0 + wn * 64 + j * 16 + lrow - 1024;
        const int h = nn >> 6, d = nn & 63;
        const int m = m0 + wm * 64 + i * 16 + lgrp * 4;
        const int b = m >> 11, s0 = m & 2047;
        bf16x4 pk;
#pragma unroll
        for (int r = 0; r < 4; r++) pk[r] = (__bf16)acc[i][j][r];
        *(bf16x4*)(vt + ((size_t)((b * 16 + h) * 64 + d)) * 2048 + s0) = pk;
      }
    }
  } else {  // MODE 1
#pragma unroll
    for (int i = 0; i < 4; i++)
#pragma unroll
      for (int j = 0; j < 4; j++) {
        const int n = n0 + wn * 64 + j * 16 + lrow;
#pragma unroll
        for (int r = 0; r < 4; r++) {
          const int m = m0 + wm * 64 + i * 16 + lgrp * 4 + r;
          Cf[(size_t)m * N + n] = acc[i][j][r];
        }
      }
  }
}

// ---------------- flash attention (no K/V LDS staging: direct-from-L2 fragments) -------
// grid (16, 64) XCD-swizzled (8 bh per XCD = 4MB K/V working set = one L2).
// 4 independent waves (no barriers); wave owns 32 q-rows; KV tiles 64.
// Swapped QK^T (mfma(K,Q)): lane holds q=lane&15, kv = t*16 + lgrp*4 + r.
// Softmax: in-lane 16-max + 2 shfl; defer-max THR=8; exp2 with log2-domain m.
// P via per-wave sP (8KB LDS, swizzled); V fragments loaded at tile top (issue-early).
__global__ __launch_bounds__(256) void attn_kernel(const __bf16* __restrict__ qm,
                                                   const __bf16* __restrict__ km,
                                                   const __bf16* __restrict__ vtm,
                                                   __bf16* __restrict__ o) {
  constexpr float LOG2E = 1.44269504f;
  const int lin = blockIdx.y * gridDim.x + blockIdx.x;  // 1024 blocks
  const int swz = (lin & 7) * 128 + (lin >> 3);         // bijective, groups bh per XCD
  const int qb = swz & 15;
  const int bh = swz >> 4;
  const int b = bh >> 4, h = bh & 15;
  const int q0 = qb * 128;
  const int tid = threadIdx.x, wave = tid >> 6, lane = tid & 63;
  const int lrow = lane & 15, lgrp = lane >> 4;

  __shared__ __bf16 sP[4][16 * 64];  // per-wave region: no barriers needed

  const __bf16* kbase  = km + (size_t)(b * S_) * 1024 + h * 64 + (size_t)lrow * 1024 + lgrp * 8;
  const __bf16* vbase  = vtm + (size_t)((b * 16 + h) * 64) * 2048 + (size_t)lrow * 2048 + lgrp * 8;

  // Q fragments in registers (2 row-tiles x 2 k-halves)
  bf16x8 qf[2][2];
#pragma unroll
  for (int rt = 0; rt < 2; ++rt) {
    const __bf16* qp = qm + (size_t)(b * S_ + q0 + wave * 32 + rt * 16 + lrow) * 1024 + h * 64;
    qf[rt][0] = *(const bf16x8*)(qp + 8 * lgrp);
    qf[rt][1] = *(const bf16x8*)(qp + 32 + 8 * lgrp);
  }

  f32x4 accd[2][4];
#pragma unroll
  for (int rt = 0; rt < 2; ++rt)
#pragma unroll
    for (int dt = 0; dt < 4; ++dt) accd[rt][dt] = f32x4{0.f, 0.f, 0.f, 0.f};
  float m_r[2], m2_r[2], l_r[2];
#pragma unroll
  for (int rt = 0; rt < 2; ++rt) { m_r[rt] = -1e30f; m2_r[rt] = -1e30f; l_r[rt] = 0.f; }

  for (int kt = 0; kt < S_ / 64; ++kt) {
    // V fragments: issue early, consumed last (L2 latency hides under QK^T+softmax)
    bf16x8 vfr[2][4];
#pragma unroll
    for (int half = 0; half < 2; ++half)
#pragma unroll
      for (int dt = 0; dt < 4; ++dt)
        vfr[half][dt] = *(const bf16x8*)(vbase + (size_t)dt * 16 * 2048 + kt * 64 + half * 32);

    // QK^T (swapped): sc[rt][t] = C[kv-block t][q]; K fragments direct from L2
    f32x4 sc[2][4];
#pragma unroll
    for (int rt = 0; rt < 2; ++rt)
#pragma unroll
      for (int t = 0; t < 4; ++t) sc[rt][t] = f32x4{0.f, 0.f, 0.f, 0.f};
#pragma unroll
    for (int t = 0; t < 4; ++t) {
#pragma unroll
      for (int kk = 0; kk < 2; ++kk) {
        bf16x8 kf = *(const bf16x8*)(kbase + (size_t)(kt * 64 + t * 16) * 1024 + kk * 32);
        sc[0][t] = __builtin_amdgcn_mfma_f32_16x16x32_bf16(kf, qf[0][kk], sc[0][t], 0, 0, 0);
        sc[1][t] = __builtin_amdgcn_mfma_f32_16x16x32_bf16(kf, qf[1][kk], sc[1][t], 0, 0, 0);
      }
    }

#pragma unroll
    for (int rt = 0; rt < 2; ++rt) {
      // row max: 15 in-lane + 2 shfl (replicas at lane^16, lane^32)
      f32x4 mm = fmax4(fmax4(sc[rt][0], sc[rt][1]), fmax4(sc[rt][2], sc[rt][3]));
      float tm = fmaxf(fmaxf(mm[0], mm[1]), fmaxf(mm[2], mm[3]));
      tm = fmaxf(tm, __shfl_xor(tm, 16, 64));
      tm = fmaxf(tm, __shfl_xor(tm, 32, 64));

      // defer-max: only rescale when tile max grows by > 8 (P bounded by e^8)
      if (!__all(tm - m_r[rt] <= 8.0f)) {
        const float mn = fmaxf(m_r[rt], tm);
        const float scl = __builtin_exp2f((m_r[rt] - mn) * LOG2E);
        m_r[rt] = mn;
        m2_r[rt] = mn * LOG2E;
        l_r[rt] *= scl;
        float sclr[4];
#pragma unroll
        for (int j = 0; j < 4; ++j) sclr[j] = __shfl(scl, lgrp * 4 + j, 64);
#pragma unroll
        for (int dt = 0; dt < 4; ++dt)
#pragma unroll
          for (int j = 0; j < 4; ++j) accd[rt][dt][j] *= sclr[j];
      }

      // p = exp2(s*log2e - m2): 1 FMA + 1 exp2 per element
      float ps0 = 0.f, ps1 = 0.f;
      const float nm2 = -m2_r[rt];
#pragma unroll
      for (int t = 0; t < 4; ++t) {
        bf16x4 pk;
        const float p0 = __builtin_exp2f(fmaf(sc[rt][t][0], LOG2E, nm2));
        const float p1 = __builtin_exp2f(fmaf(sc[rt][t][1], LOG2E, nm2));
        const float p2 = __builtin_exp2f(fmaf(sc[rt][t][2], LOG2E, nm2));
        const float p3 = __builtin_exp2f(fmaf(sc[rt][t][3], LOG2E, nm2));
        ps0 += p0 + p2; ps1 += p1 + p3;
        pk[0] = (__bf16)p0; pk[1] = (__bf16)p1; pk[2] = (__bf16)p2; pk[3] = (__bf16)p3;
        *(bf16x4*)(&sP[wave][lrow * 64 + (((2 * t + (lgrp >> 1)) ^ (lrow & 7)) << 3) +
                             ((lgrp & 1) << 2)]) = pk;
      }
      float ps = ps0 + ps1;
      ps += __shfl_xor(ps, 16, 64);
      ps += __shfl_xor(ps, 32, 64);
      l_r[rt] += ps;

      // PV: V fragments already in registers
#pragma unroll
      for (int half = 0; half < 2; ++half) {
        bf16x8 pf = *(const bf16x8*)(&sP[wave][lrow * 64 + (((half * 4 + lgrp) ^ (lrow & 7)) << 3)]);
#pragma unroll
        for (int dt = 0; dt < 4; ++dt)
          accd[rt][dt] = __builtin_amdgcn_mfma_f32_16x16x32_bf16(pf, vfr[half][dt], accd[rt][dt], 0, 0, 0);
      }
    }
  }

  // epilogue: broadcast l from owner lanes, divide, store bf16
#pragma unroll
  for (int rt = 0; rt < 2; ++rt) {
#pragma unroll
    for (int j = 0; j < 4; ++j) {
      const float lv = __shfl(l_r[rt], lgrp * 4 + j, 64);
      const float inv = 1.f / lv;
      const int row = b * S_ + q0 + wave * 32 + rt * 16 + lgrp * 4 + j;
      __bf16* ob = o + (size_t)row * 1024 + h * 64;
#pragma unroll
      for (int dt = 0; dt < 4; ++dt) ob[dt * 16 + lrow] = (__bf16)(accd[rt][dt][j] * inv);
    }
  }
}

extern "C" void kernel_launch(void* const* d_in, const int* in_sizes, int n_in,
                              void* d_out, int out_size, void* d_ws, size_t ws_size,
                              hipStream_t stream) {
  (void)in_sizes; (void)n_in; (void)out_size; (void)ws_size;
  const float* x       = (const float*)d_in[0];
  const float* q_w     = (const float*)d_in[1];
  const float* q_b     = (const float*)d_in[2];
  const float* kv_w    = (const float*)d_in[3];
  const float* kv_b    = (const float*)d_in[4];
  const float* gamma_q = (const float*)d_in[5];
  const float* gamma_k = (const float*)d_in[6];
  const float* out_w   = (const float*)d_in[7];
  float* out = (float*)d_out;

  char* ws = (char*)d_ws;
  __bf16* x_bf   = (__bf16*)(ws);                  // 16 MB [8192,1024]
  __bf16* qw_bf  = (__bf16*)(ws + (16ull << 20));  // 2 MB
  __bf16* kvw_bf = (__bf16*)(ws + (18ull << 20));  // 4 MB
  __bf16* ow_bf  = (__bf16*)(ws + (22ull << 20));  // 2 MB
  __bf16* q_bf   = (__bf16*)(ws + (24ull << 20));  // 16 MB [8192,1024] normalized q
  __bf16* k_bf   = (__bf16*)(ws + (40ull << 20));  // 16 MB [8192,1024] normalized k
  __bf16* vt_bf  = (__bf16*)(ws + (56ull << 20));  // 16 MB [B,H,D,S]
  __bf16* at_bf  = (__bf16*)(ws + (72ull << 20));  // 16 MB [8192,1024]

  cvt_bf16<<<8192, 256, 0, stream>>>(x, x_bf);
  cvt_bf16<<<1024, 256, 0, stream>>>(q_w, qw_bf);
  cvt_bf16<<<2048, 256, 0, stream>>>(kv_w, kvw_bf);
  cvt_bf16<<<1024, 256, 0, stream>>>(out_w, ow_bf);

  gemm_bt<2><<<dim3(8, 64), 256, 0, stream>>>(x_bf, qw_bf, q_b, gamma_q, q_bf, nullptr, nullptr,
                                              8192, 1024, 1024);
  gemm_bt<3><<<dim3(16, 64), 256, 0, stream>>>(x_bf, kvw_bf, kv_b, gamma_k, k_bf, nullptr, vt_bf,
                                               8192, 2048, 1024);

  attn_kernel<<<dim3(16, 64), 256, 0, stream>>>(q_bf, k_bf, vt_bf, at_bf);

  gemm_bt<1><<<dim3(8, 64), 256, 0, stream>>>(at_bf, ow_bf, nullptr, nullptr, nullptr, out, nullptr,
                                              8192, 1024, 1024);
}

// Round 5
// 344.245 us; speedup vs baseline: 1.3239x; 1.3239x over previous
//
#include <hip/hip_runtime.h>
#include <stdint.h>

#define B_ 4
#define S_ 2048
#define HID_ 1024
#define NH_ 16
#define HD_ 64

typedef __bf16 bf16x8 __attribute__((ext_vector_type(8)));
typedef __bf16 bf16x4 __attribute__((ext_vector_type(4)));
typedef float f32x4 __attribute__((ext_vector_type(4)));

__device__ inline void gload_lds16(const void* g, void* l) {
  __builtin_amdgcn_global_load_lds((const __attribute__((address_space(1))) unsigned int*)g,
                                   (__attribute__((address_space(3))) unsigned int*)l, 16, 0, 0);
}

__device__ inline f32x4 fmax4(f32x4 a, f32x4 b) {
  f32x4 r;
  r[0] = fmaxf(a[0], b[0]); r[1] = fmaxf(a[1], b[1]);
  r[2] = fmaxf(a[2], b[2]); r[3] = fmaxf(a[3], b[3]);
  return r;
}

// ---------------- fp32 -> bf16 conversion ----------------
__global__ __launch_bounds__(256) void cvt_bf16(const float* __restrict__ in, __bf16* __restrict__ out) {
  int i = (blockIdx.x * 256 + threadIdx.x) * 4;
  f32x4 v = *(const f32x4*)(in + i);
  bf16x4 o;
  o[0] = (__bf16)v[0]; o[1] = (__bf16)v[1]; o[2] = (__bf16)v[2]; o[3] = (__bf16)v[3];
  *(bf16x4*)(out + i) = o;
}

// ---------------- GEMM: C[M,N] = A[M,K]*Bt[N,K]^T (+bias) with fused epilogues --------
// MODE 1: float out (no bias)          -> Cf[m*N+n]
// MODE 2: bias + qknorm*LOG2E, bf16    -> Cb[m*1024+n]   (q projection, log2-prescaled)
// MODE 3: kv: n<1024 bias+qknorm -> Cb (k); n>=1024 bias -> vt[B,H,D,S] transposed (v)
template <int MODE>
__global__ __launch_bounds__(256) void gemm_bt(const __bf16* __restrict__ A,
                                               const __bf16* __restrict__ Bt,
                                               const float* __restrict__ bias,
                                               const float* __restrict__ gamma,
                                               __bf16* __restrict__ Cb,
                                               float* __restrict__ Cf,
                                               __bf16* __restrict__ vt,
                                               int M, int N, int K) {
  const int n0 = blockIdx.x * 128;
  const int m0 = blockIdx.y * 128;
  const int tid  = threadIdx.x;
  const int wave = tid >> 6, lane = tid & 63;
  const int wm = wave >> 1, wn = wave & 1;
  const int lrow = lane & 15, lgrp = lane >> 4;

  __shared__ __bf16 sA[128][64];
  __shared__ __bf16 sB[128][64];

  f32x4 acc[4][4];
#pragma unroll
  for (int i = 0; i < 4; i++)
#pragma unroll
    for (int j = 0; j < 4; j++) acc[i][j] = f32x4{0.f, 0.f, 0.f, 0.f};

  for (int k0 = 0; k0 < K; k0 += 64) {
    __syncthreads();
#pragma unroll
    for (int c = 0; c < 4; c++) {
      const int row = wave * 32 + c * 8;
      const __bf16* ga = A + (size_t)(m0 + row + (lane >> 3)) * K + k0 + (lane & 7) * 8;
      gload_lds16(ga, &sA[row][0]);
      const __bf16* gb = Bt + (size_t)(n0 + row + (lane >> 3)) * K + k0 + (lane & 7) * 8;
      gload_lds16(gb, &sB[row][0]);
    }
    __syncthreads();
#pragma unroll
    for (int kk = 0; kk < 2; kk++) {
      bf16x8 af[4], bfr[4];
#pragma unroll
      for (int i = 0; i < 4; i++) {
        af[i]  = *(const bf16x8*)(&sA[wm * 64 + i * 16 + lrow][kk * 32 + 8 * lgrp]);
        bfr[i] = *(const bf16x8*)(&sB[wn * 64 + i * 16 + lrow][kk * 32 + 8 * lgrp]);
      }
#pragma unroll
      for (int i = 0; i < 4; i++)
#pragma unroll
        for (int j = 0; j < 4; j++)
          acc[i][j] = __builtin_amdgcn_mfma_f32_16x16x32_bf16(af[i], bfr[j], acc[i][j], 0, 0, 0);
    }
  }

  // ---- epilogue ----
  if (MODE != 1) {
    float bv[4];
#pragma unroll
    for (int j = 0; j < 4; j++) bv[j] = bias[n0 + wn * 64 + j * 16 + lrow];
#pragma unroll
    for (int i = 0; i < 4; i++)
#pragma unroll
      for (int j = 0; j < 4; j++)
#pragma unroll
        for (int r = 0; r < 4; r++) acc[i][j][r] += bv[j];
  }

  const bool do_norm = (MODE == 2) || (MODE == 3 && n0 < 1024);
  if (do_norm) {
    // q gets an extra LOG2E so attention scores arrive in log2 domain
    const float nscale = (MODE == 2) ? 8.f * 1.44269504f : 8.f;
    float g[4];
#pragma unroll
    for (int j = 0; j < 4; j++) g[j] = gamma[(n0 + wn * 64 + j * 16 + lrow) & 1023];
#pragma unroll
    for (int i = 0; i < 4; i++) {
#pragma unroll
      for (int r = 0; r < 4; r++) {
        float ss = acc[i][0][r] * acc[i][0][r] + acc[i][1][r] * acc[i][1][r] +
                   acc[i][2][r] * acc[i][2][r] + acc[i][3][r] * acc[i][3][r];
#pragma unroll
        for (int off = 1; off < 16; off <<= 1) ss += __shfl_xor(ss, off, 64);
        const float inv = nscale / fmaxf(sqrtf(ss), 1e-12f);
        const int m = m0 + wm * 64 + i * 16 + lgrp * 4 + r;
#pragma unroll
        for (int j = 0; j < 4; j++) {
          const int n = (n0 + wn * 64 + j * 16 + lrow) & 1023;
          Cb[(size_t)m * 1024 + n] = (__bf16)(acc[i][j][r] * inv * g[j]);
        }
      }
    }
  } else if (MODE == 3) {
    // v half: write transposed vt[b][h][d][s], packed 4 consecutive s per store
#pragma unroll
    for (int i = 0; i < 4; i++) {
#pragma unroll
      for (int j = 0; j < 4; j++) {
        const int nn = n0 + wn * 64 + j * 16 + lrow - 1024;
        const int h = nn >> 6, d = nn & 63;
        const int m = m0 + wm * 64 + i * 16 + lgrp * 4;
        const int b = m >> 11, s0 = m & 2047;
        bf16x4 pk;
#pragma unroll
        for (int r = 0; r < 4; r++) pk[r] = (__bf16)acc[i][j][r];
        *(bf16x4*)(vt + ((size_t)((b * 16 + h) * 64 + d)) * 2048 + s0) = pk;
      }
    }
  } else {  // MODE 1
#pragma unroll
    for (int i = 0; i < 4; i++)
#pragma unroll
      for (int j = 0; j < 4; j++) {
        const int n = n0 + wn * 64 + j * 16 + lrow;
#pragma unroll
        for (int r = 0; r < 4; r++) {
          const int m = m0 + wm * 64 + i * 16 + lgrp * 4 + r;
          Cf[(size_t)m * N + n] = acc[i][j][r];
        }
      }
  }
}

// ---------------- flash attention (staged, 8 waves, log2 softmax, defer-max) ----------
// grid (8, 64) XCD-swizzled; 8 waves / 512 threads; block owns 256 q rows (wave: 32).
// K/Vt LDS-staged (double-buffered, global_load_lds, XOR-swizzled via pre-swizzled src).
// Swapped QK^T (mfma(K,Q)): lane holds q=lane&15, kv = t*16 + lgrp*4 + r; q pre-scaled
// by LOG2E so softmax is exp2-only. Defer-max THR = 8*LOG2E. setprio around MFMA.
__global__ __launch_bounds__(512) void attn_kernel(const __bf16* __restrict__ qm,
                                                   const __bf16* __restrict__ km,
                                                   const __bf16* __restrict__ vtm,
                                                   __bf16* __restrict__ o) {
  constexpr float THR = 11.5416f;  // 8 * log2(e)
  const int lin = blockIdx.y * gridDim.x + blockIdx.x;  // 512 blocks
  const int swz = (lin & 7) * 64 + (lin >> 3);          // bijective; 8 bh per XCD (4MB = L2)
  const int qb = swz & 7;
  const int bh = swz >> 3;
  const int b = bh >> 4, h = bh & 15;
  const int q0 = qb * 256;
  const int tid = threadIdx.x, wave = tid >> 6, lane = tid & 63;
  const int lrow = lane & 15, lgrp = lane >> 4;

  __shared__ __bf16 sK[2][64 * 64];
  __shared__ __bf16 sVt[2][64 * 64];
  __shared__ __bf16 sP[8][2][16 * 64];

  const __bf16* kbase  = km + (size_t)(b * S_) * 1024 + h * 64;
  const __bf16* vtbase = vtm + (size_t)((b * 16 + h) * 64) * 2048;

  const int srow = lane >> 3;   // 0..7
  const int pchunk = lane & 7;  // 16B chunk within 128B row

  auto stage = [&](int buf, int kt) {
    const int rr = wave * 8;    // wave-uniform base row; 8 waves cover 64 rows
    const int r = rr + srow;
    gload_lds16(kbase + (size_t)(kt * 64 + r) * 1024 + ((pchunk ^ (r & 7)) << 3),
                &sK[buf][rr * 64]);
    gload_lds16(vtbase + (size_t)r * 2048 + kt * 64 + ((pchunk ^ (r & 7)) << 3),
                &sVt[buf][rr * 64]);
  };

  // Q fragments (2 row-tiles x 2 k-halves)
  bf16x8 qf[2][2];
#pragma unroll
  for (int rt = 0; rt < 2; ++rt) {
    const __bf16* qp = qm + (size_t)(b * S_ + q0 + wave * 32 + rt * 16 + lrow) * 1024 + h * 64;
    qf[rt][0] = *(const bf16x8*)(qp + 8 * lgrp);
    qf[rt][1] = *(const bf16x8*)(qp + 32 + 8 * lgrp);
  }

  f32x4 accd[2][4];
#pragma unroll
  for (int rt = 0; rt < 2; ++rt)
#pragma unroll
    for (int dt = 0; dt < 4; ++dt) accd[rt][dt] = f32x4{0.f, 0.f, 0.f, 0.f};
  float m_r[2], l_r[2];
#pragma unroll
  for (int rt = 0; rt < 2; ++rt) { m_r[rt] = -1e30f; l_r[rt] = 0.f; }

  stage(0, 0);
  int buf = 0;
  for (int kt = 0; kt < S_ / 64; ++kt) {
    __syncthreads();                       // drains vmcnt: tile kt ready
    if (kt + 1 < S_ / 64) stage(buf ^ 1, kt + 1);

    // QK^T (swapped): sc[rt][t] = C[kv-block t][q]
    f32x4 sc[2][4];
#pragma unroll
    for (int rt = 0; rt < 2; ++rt)
#pragma unroll
      for (int t = 0; t < 4; ++t) sc[rt][t] = f32x4{0.f, 0.f, 0.f, 0.f};
    __builtin_amdgcn_s_setprio(1);
#pragma unroll
    for (int t = 0; t < 4; ++t) {
      const int krow = t * 16 + lrow;
#pragma unroll
      for (int kk = 0; kk < 2; ++kk) {
        bf16x8 kf = *(const bf16x8*)(&sK[buf][krow * 64 + (((kk * 4 + lgrp) ^ (krow & 7)) << 3)]);
        sc[0][t] = __builtin_amdgcn_mfma_f32_16x16x32_bf16(kf, qf[0][kk], sc[0][t], 0, 0, 0);
        sc[1][t] = __builtin_amdgcn_mfma_f32_16x16x32_bf16(kf, qf[1][kk], sc[1][t], 0, 0, 0);
      }
    }
    __builtin_amdgcn_s_setprio(0);

    // softmax (log2 domain) + P writes, both row-tiles
#pragma unroll
    for (int rt = 0; rt < 2; ++rt) {
      f32x4 mm = fmax4(fmax4(sc[rt][0], sc[rt][1]), fmax4(sc[rt][2], sc[rt][3]));
      float tm = fmaxf(fmaxf(mm[0], mm[1]), fmaxf(mm[2], mm[3]));
      tm = fmaxf(tm, __shfl_xor(tm, 16, 64));
      tm = fmaxf(tm, __shfl_xor(tm, 32, 64));

      if (!__all(tm - m_r[rt] <= THR)) {      // defer-max: rescale only on real growth
        const float mn = fmaxf(m_r[rt], tm);
        const float scl = __builtin_exp2f(m_r[rt] - mn);
        m_r[rt] = mn;
        l_r[rt] *= scl;
        float sclr[4];
#pragma unroll
        for (int j = 0; j < 4; ++j) sclr[j] = __shfl(scl, lgrp * 4 + j, 64);
#pragma unroll
        for (int dt = 0; dt < 4; ++dt)
#pragma unroll
          for (int j = 0; j < 4; ++j) accd[rt][dt][j] *= sclr[j];
      }

      const float nm = m_r[rt];
      float ps0 = 0.f, ps1 = 0.f;
#pragma unroll
      for (int t = 0; t < 4; ++t) {
        bf16x4 pk;
        const float p0 = __builtin_exp2f(sc[rt][t][0] - nm);
        const float p1 = __builtin_exp2f(sc[rt][t][1] - nm);
        const float p2 = __builtin_exp2f(sc[rt][t][2] - nm);
        const float p3 = __builtin_exp2f(sc[rt][t][3] - nm);
        ps0 += p0 + p2; ps1 += p1 + p3;
        pk[0] = (__bf16)p0; pk[1] = (__bf16)p1; pk[2] = (__bf16)p2; pk[3] = (__bf16)p3;
        *(bf16x4*)(&sP[wave][rt][lrow * 64 + (((2 * t + (lgrp >> 1)) ^ (lrow & 7)) << 3) +
                                ((lgrp & 1) << 2)]) = pk;
      }
      float ps = ps0 + ps1;
      ps += __shfl_xor(ps, 16, 64);
      ps += __shfl_xor(ps, 32, 64);
      l_r[rt] += ps;
    }

    // PV: V fragments loaded per half, shared across both row-tiles
    __builtin_amdgcn_s_setprio(1);
#pragma unroll
    for (int half = 0; half < 2; ++half) {
      bf16x8 vf[4];
#pragma unroll
      for (int dt = 0; dt < 4; ++dt) {
        const int d = dt * 16 + lrow;
        vf[dt] = *(const bf16x8*)(&sVt[buf][d * 64 + (((half * 4 + lgrp) ^ (lrow & 7)) << 3)]);
      }
#pragma unroll
      for (int rt = 0; rt < 2; ++rt) {
        bf16x8 pf = *(const bf16x8*)(&sP[wave][rt][lrow * 64 + (((half * 4 + lgrp) ^ (lrow & 7)) << 3)]);
#pragma unroll
        for (int dt = 0; dt < 4; ++dt)
          accd[rt][dt] = __builtin_amdgcn_mfma_f32_16x16x32_bf16(pf, vf[dt], accd[rt][dt], 0, 0, 0);
      }
    }
    __builtin_amdgcn_s_setprio(0);
    buf ^= 1;
  }

  // epilogue: broadcast l from owner lanes, divide, store bf16
#pragma unroll
  for (int rt = 0; rt < 2; ++rt) {
#pragma unroll
    for (int j = 0; j < 4; ++j) {
      const float lv = __shfl(l_r[rt], lgrp * 4 + j, 64);
      const float inv = 1.f / lv;
      const int row = b * S_ + q0 + wave * 32 + rt * 16 + lgrp * 4 + j;
      __bf16* ob = o + (size_t)row * 1024 + h * 64;
#pragma unroll
      for (int dt = 0; dt < 4; ++dt) ob[dt * 16 + lrow] = (__bf16)(accd[rt][dt][j] * inv);
    }
  }
}

extern "C" void kernel_launch(void* const* d_in, const int* in_sizes, int n_in,
                              void* d_out, int out_size, void* d_ws, size_t ws_size,
                              hipStream_t stream) {
  (void)in_sizes; (void)n_in; (void)out_size; (void)ws_size;
  const float* x       = (const float*)d_in[0];
  const float* q_w     = (const float*)d_in[1];
  const float* q_b     = (const float*)d_in[2];
  const float* kv_w    = (const float*)d_in[3];
  const float* kv_b    = (const float*)d_in[4];
  const float* gamma_q = (const float*)d_in[5];
  const float* gamma_k = (const float*)d_in[6];
  const float* out_w   = (const float*)d_in[7];
  float* out = (float*)d_out;

  char* ws = (char*)d_ws;
  __bf16* x_bf   = (__bf16*)(ws);                  // 16 MB [8192,1024]
  __bf16* qw_bf  = (__bf16*)(ws + (16ull << 20));  // 2 MB
  __bf16* kvw_bf = (__bf16*)(ws + (18ull << 20));  // 4 MB
  __bf16* ow_bf  = (__bf16*)(ws + (22ull << 20));  // 2 MB
  __bf16* q_bf   = (__bf16*)(ws + (24ull << 20));  // 16 MB [8192,1024] normalized q (log2-prescaled)
  __bf16* k_bf   = (__bf16*)(ws + (40ull << 20));  // 16 MB [8192,1024] normalized k
  __bf16* vt_bf  = (__bf16*)(ws + (56ull << 20));  // 16 MB [B,H,D,S]
  __bf16* at_bf  = (__bf16*)(ws + (72ull << 20));  // 16 MB [8192,1024]

  cvt_bf16<<<8192, 256, 0, stream>>>(x, x_bf);
  cvt_bf16<<<1024, 256, 0, stream>>>(q_w, qw_bf);
  cvt_bf16<<<2048, 256, 0, stream>>>(kv_w, kvw_bf);
  cvt_bf16<<<1024, 256, 0, stream>>>(out_w, ow_bf);

  gemm_bt<2><<<dim3(8, 64), 256, 0, stream>>>(x_bf, qw_bf, q_b, gamma_q, q_bf, nullptr, nullptr,
                                              8192, 1024, 1024);
  gemm_bt<3><<<dim3(16, 64), 256, 0, stream>>>(x_bf, kvw_bf, kv_b, gamma_k, k_bf, nullptr, vt_bf,
                                               8192, 2048, 1024);

  attn_kernel<<<dim3(8, 64), 512, 0, stream>>>(q_bf, k_bf, vt_bf, at_bf);

  gemm_bt<1><<<dim3(8, 64), 256, 0, stream>>>(at_bf, ow_bf, nullptr, nullptr, nullptr, out, nullptr,
                                              8192, 1024, 1024);
}

// Round 6
// 341.220 us; speedup vs baseline: 1.3356x; 1.0089x over previous
//
#include <hip/hip_runtime.h>
#include <stdint.h>

#define B_ 4
#define S_ 2048
#define HID_ 1024
#define NH_ 16
#define HD_ 64

typedef __bf16 bf16x8 __attribute__((ext_vector_type(8)));
typedef __bf16 bf16x4 __attribute__((ext_vector_type(4)));
typedef float f32x4 __attribute__((ext_vector_type(4)));

__device__ inline void gload_lds16(const void* g, void* l) {
  __builtin_amdgcn_global_load_lds((const __attribute__((address_space(1))) unsigned int*)g,
                                   (__attribute__((address_space(3))) unsigned int*)l, 16, 0, 0);
}

__device__ inline f32x4 fmax4(f32x4 a, f32x4 b) {
  f32x4 r;
  r[0] = fmaxf(a[0], b[0]); r[1] = fmaxf(a[1], b[1]);
  r[2] = fmaxf(a[2], b[2]); r[3] = fmaxf(a[3], b[3]);
  return r;
}

// ---------------- fp32 -> bf16 conversion ----------------
__global__ __launch_bounds__(256) void cvt_bf16(const float* __restrict__ in, __bf16* __restrict__ out) {
  int i = (blockIdx.x * 256 + threadIdx.x) * 4;
  f32x4 v = *(const f32x4*)(in + i);
  bf16x4 o;
  o[0] = (__bf16)v[0]; o[1] = (__bf16)v[1]; o[2] = (__bf16)v[2]; o[3] = (__bf16)v[3];
  *(bf16x4*)(out + i) = o;
}

// ---------------- GEMM: C[M,N] = A[M,K]*Bt[N,K]^T (+bias) with fused epilogues --------
// MODE 1: float out, no bias -> Cf[m*N+n]                          (out projection)
// MODE 4: fused qkv, N=3072:
//         n0<1024:   bias q_b, qknorm*gamma_q*8*LOG2E -> Cq[m*1024+n]
//         1024..2047: bias kv_b, qknorm*gamma_k*8      -> Ck[m*1024+(n&1023)]
//         >=2048:    bias kv_b -> vt[b][h][d][s] transposed
template <int MODE>
__global__ __launch_bounds__(256) void gemm_bt(const __bf16* __restrict__ A,
                                               const __bf16* __restrict__ Bt,
                                               const float* __restrict__ bias_q,
                                               const float* __restrict__ bias_kv,
                                               const float* __restrict__ gamma_q,
                                               const float* __restrict__ gamma_k,
                                               __bf16* __restrict__ Cq,
                                               __bf16* __restrict__ Ck,
                                               float* __restrict__ Cf,
                                               __bf16* __restrict__ vt,
                                               int M, int N, int K) {
  const int n0 = blockIdx.x * 128;
  const int m0 = blockIdx.y * 128;
  const int tid  = threadIdx.x;
  const int wave = tid >> 6, lane = tid & 63;
  const int wm = wave >> 1, wn = wave & 1;
  const int lrow = lane & 15, lgrp = lane >> 4;

  __shared__ __bf16 sA[128][64];
  __shared__ __bf16 sB[128][64];

  f32x4 acc[4][4];
#pragma unroll
  for (int i = 0; i < 4; i++)
#pragma unroll
    for (int j = 0; j < 4; j++) acc[i][j] = f32x4{0.f, 0.f, 0.f, 0.f};

  for (int k0 = 0; k0 < K; k0 += 64) {
    __syncthreads();
#pragma unroll
    for (int c = 0; c < 4; c++) {
      const int row = wave * 32 + c * 8;
      const __bf16* ga = A + (size_t)(m0 + row + (lane >> 3)) * K + k0 + (lane & 7) * 8;
      gload_lds16(ga, &sA[row][0]);
      const __bf16* gb = Bt + (size_t)(n0 + row + (lane >> 3)) * K + k0 + (lane & 7) * 8;
      gload_lds16(gb, &sB[row][0]);
    }
    __syncthreads();
#pragma unroll
    for (int kk = 0; kk < 2; kk++) {
      bf16x8 af[4], bfr[4];
#pragma unroll
      for (int i = 0; i < 4; i++) {
        af[i]  = *(const bf16x8*)(&sA[wm * 64 + i * 16 + lrow][kk * 32 + 8 * lgrp]);
        bfr[i] = *(const bf16x8*)(&sB[wn * 64 + i * 16 + lrow][kk * 32 + 8 * lgrp]);
      }
#pragma unroll
      for (int i = 0; i < 4; i++)
#pragma unroll
        for (int j = 0; j < 4; j++)
          acc[i][j] = __builtin_amdgcn_mfma_f32_16x16x32_bf16(af[i], bfr[j], acc[i][j], 0, 0, 0);
    }
  }

  // ---- epilogue ----
  if (MODE == 4) {
    float bv[4];
#pragma unroll
    for (int j = 0; j < 4; j++) {
      const int n = n0 + wn * 64 + j * 16 + lrow;
      bv[j] = (n < 1024) ? bias_q[n] : bias_kv[n - 1024];
    }
#pragma unroll
    for (int i = 0; i < 4; i++)
#pragma unroll
      for (int j = 0; j < 4; j++)
#pragma unroll
        for (int r = 0; r < 4; r++) acc[i][j][r] += bv[j];

    const int nblk = n0 >> 10;  // 0: q, 1: k, 2: v (uniform per block)
    if (nblk < 2) {
      const float nscale = (nblk == 0) ? 8.f * 1.44269504f : 8.f;
      const float* gam = (nblk == 0) ? gamma_q : gamma_k;
      __bf16* dst = (nblk == 0) ? Cq : Ck;
      float g[4];
#pragma unroll
      for (int j = 0; j < 4; j++) g[j] = gam[(n0 + wn * 64 + j * 16 + lrow) & 1023];
#pragma unroll
      for (int i = 0; i < 4; i++) {
#pragma unroll
        for (int r = 0; r < 4; r++) {
          float ss = acc[i][0][r] * acc[i][0][r] + acc[i][1][r] * acc[i][1][r] +
                     acc[i][2][r] * acc[i][2][r] + acc[i][3][r] * acc[i][3][r];
#pragma unroll
          for (int off = 1; off < 16; off <<= 1) ss += __shfl_xor(ss, off, 64);
          const float inv = nscale / fmaxf(sqrtf(ss), 1e-12f);
          const int m = m0 + wm * 64 + i * 16 + lgrp * 4 + r;
#pragma unroll
          for (int j = 0; j < 4; j++) {
            const int n = (n0 + wn * 64 + j * 16 + lrow) & 1023;
            dst[(size_t)m * 1024 + n] = (__bf16)(acc[i][j][r] * inv * g[j]);
          }
        }
      }
    } else {
      // v: write transposed vt[b][h][d][s], packed 4 consecutive s per store
#pragma unroll
      for (int i = 0; i < 4; i++) {
#pragma unroll
        for (int j = 0; j < 4; j++) {
          const int nn = n0 + wn * 64 + j * 16 + lrow - 2048;
          const int h = nn >> 6, d = nn & 63;
          const int m = m0 + wm * 64 + i * 16 + lgrp * 4;
          const int b = m >> 11, s0 = m & 2047;
          bf16x4 pk;
#pragma unroll
          for (int r = 0; r < 4; r++) pk[r] = (__bf16)acc[i][j][r];
          *(bf16x4*)(vt + ((size_t)((b * 16 + h) * 64 + d)) * 2048 + s0) = pk;
        }
      }
    }
  } else {  // MODE 1
#pragma unroll
    for (int i = 0; i < 4; i++)
#pragma unroll
      for (int j = 0; j < 4; j++) {
        const int n = n0 + wn * 64 + j * 16 + lrow;
#pragma unroll
        for (int r = 0; r < 4; r++) {
          const int m = m0 + wm * 64 + i * 16 + lgrp * 4 + r;
          Cf[(size_t)m * N + n] = acc[i][j][r];
        }
      }
  }
}

// ---------------- flash attention (staged, 8 waves, single-rt sP: 48KB LDS) ----------
// grid (8, 64) XCD-swizzled; 8 waves / 512 threads; block owns 256 q rows (wave: 32).
// K/Vt LDS-staged (double-buffered, global_load_lds, XOR-swizzled via pre-swizzled src).
// Swapped QK^T (mfma(K,Q)): lane holds q=lane&15, kv = t*16 + lgrp*4 + r; q pre-scaled
// by LOG2E so softmax is exp2-only. Defer-max THR = 8*LOG2E.
// Per row-tile: softmax -> P to per-wave sP (16KB total) -> PV immediately (wave-
// private, no barrier). 48KB LDS => 3 blocks/CU (24 waves) vs R4's 2 (16 waves).
__global__ __launch_bounds__(512) void attn_kernel(const __bf16* __restrict__ qm,
                                                   const __bf16* __restrict__ km,
                                                   const __bf16* __restrict__ vtm,
                                                   __bf16* __restrict__ o) {
  constexpr float THR = 11.5416f;  // 8 * log2(e)
  const int lin = blockIdx.y * gridDim.x + blockIdx.x;  // 512 blocks
  const int swz = (lin & 7) * 64 + (lin >> 3);          // bijective; 8 bh per XCD (4MB = L2)
  const int qb = swz & 7;
  const int bh = swz >> 3;
  const int b = bh >> 4, h = bh & 15;
  const int q0 = qb * 256;
  const int tid = threadIdx.x, wave = tid >> 6, lane = tid & 63;
  const int lrow = lane & 15, lgrp = lane >> 4;

  __shared__ __bf16 sK[2][64 * 64];
  __shared__ __bf16 sVt[2][64 * 64];
  __shared__ __bf16 sP[8][16 * 64];

  const __bf16* kbase  = km + (size_t)(b * S_) * 1024 + h * 64;
  const __bf16* vtbase = vtm + (size_t)((b * 16 + h) * 64) * 2048;

  const int srow = lane >> 3;   // 0..7
  const int pchunk = lane & 7;  // 16B chunk within 128B row

  auto stage = [&](int buf, int kt) {
    const int rr = wave * 8;    // wave-uniform base row; 8 waves cover 64 rows
    const int r = rr + srow;
    gload_lds16(kbase + (size_t)(kt * 64 + r) * 1024 + ((pchunk ^ (r & 7)) << 3),
                &sK[buf][rr * 64]);
    gload_lds16(vtbase + (size_t)r * 2048 + kt * 64 + ((pchunk ^ (r & 7)) << 3),
                &sVt[buf][rr * 64]);
  };

  // Q fragments (2 row-tiles x 2 k-halves)
  bf16x8 qf[2][2];
#pragma unroll
  for (int rt = 0; rt < 2; ++rt) {
    const __bf16* qp = qm + (size_t)(b * S_ + q0 + wave * 32 + rt * 16 + lrow) * 1024 + h * 64;
    qf[rt][0] = *(const bf16x8*)(qp + 8 * lgrp);
    qf[rt][1] = *(const bf16x8*)(qp + 32 + 8 * lgrp);
  }

  f32x4 accd[2][4];
#pragma unroll
  for (int rt = 0; rt < 2; ++rt)
#pragma unroll
    for (int dt = 0; dt < 4; ++dt) accd[rt][dt] = f32x4{0.f, 0.f, 0.f, 0.f};
  float m_r[2], l_r[2];
#pragma unroll
  for (int rt = 0; rt < 2; ++rt) { m_r[rt] = -1e30f; l_r[rt] = 0.f; }

  stage(0, 0);
  int buf = 0;
  for (int kt = 0; kt < S_ / 64; ++kt) {
    __syncthreads();                       // drains vmcnt: tile kt ready
    if (kt + 1 < S_ / 64) stage(buf ^ 1, kt + 1);

    // QK^T (swapped): sc[rt][t] = C[kv-block t][q]
    f32x4 sc[2][4];
#pragma unroll
    for (int rt = 0; rt < 2; ++rt)
#pragma unroll
      for (int t = 0; t < 4; ++t) sc[rt][t] = f32x4{0.f, 0.f, 0.f, 0.f};
    __builtin_amdgcn_s_setprio(1);
#pragma unroll
    for (int t = 0; t < 4; ++t) {
      const int krow = t * 16 + lrow;
#pragma unroll
      for (int kk = 0; kk < 2; ++kk) {
        bf16x8 kf = *(const bf16x8*)(&sK[buf][krow * 64 + (((kk * 4 + lgrp) ^ (krow & 7)) << 3)]);
        sc[0][t] = __builtin_amdgcn_mfma_f32_16x16x32_bf16(kf, qf[0][kk], sc[0][t], 0, 0, 0);
        sc[1][t] = __builtin_amdgcn_mfma_f32_16x16x32_bf16(kf, qf[1][kk], sc[1][t], 0, 0, 0);
      }
    }
    __builtin_amdgcn_s_setprio(0);

    // per row-tile: softmax -> P (wave-private LDS) -> PV (no barrier needed)
#pragma unroll
    for (int rt = 0; rt < 2; ++rt) {
      f32x4 mm = fmax4(fmax4(sc[rt][0], sc[rt][1]), fmax4(sc[rt][2], sc[rt][3]));
      float tm = fmaxf(fmaxf(mm[0], mm[1]), fmaxf(mm[2], mm[3]));
      tm = fmaxf(tm, __shfl_xor(tm, 16, 64));
      tm = fmaxf(tm, __shfl_xor(tm, 32, 64));

      if (!__all(tm - m_r[rt] <= THR)) {      // defer-max: rescale only on real growth
        const float mn = fmaxf(m_r[rt], tm);
        const float scl = __builtin_exp2f(m_r[rt] - mn);
        m_r[rt] = mn;
        l_r[rt] *= scl;
        float sclr[4];
#pragma unroll
        for (int j = 0; j < 4; ++j) sclr[j] = __shfl(scl, lgrp * 4 + j, 64);
#pragma unroll
        for (int dt = 0; dt < 4; ++dt)
#pragma unroll
          for (int j = 0; j < 4; ++j) accd[rt][dt][j] *= sclr[j];
      }

      const float nm = m_r[rt];
      float ps0 = 0.f, ps1 = 0.f;
#pragma unroll
      for (int t = 0; t < 4; ++t) {
        bf16x4 pk;
        const float p0 = __builtin_exp2f(sc[rt][t][0] - nm);
        const float p1 = __builtin_exp2f(sc[rt][t][1] - nm);
        const float p2 = __builtin_exp2f(sc[rt][t][2] - nm);
        const float p3 = __builtin_exp2f(sc[rt][t][3] - nm);
        ps0 += p0 + p2; ps1 += p1 + p3;
        pk[0] = (__bf16)p0; pk[1] = (__bf16)p1; pk[2] = (__bf16)p2; pk[3] = (__bf16)p3;
        *(bf16x4*)(&sP[wave][lrow * 64 + (((2 * t + (lgrp >> 1)) ^ (lrow & 7)) << 3) +
                             ((lgrp & 1) << 2)]) = pk;
      }
      float ps = ps0 + ps1;
      ps += __shfl_xor(ps, 16, 64);
      ps += __shfl_xor(ps, 32, 64);
      l_r[rt] += ps;

      // PV for this row-tile
      __builtin_amdgcn_s_setprio(1);
#pragma unroll
      for (int half = 0; half < 2; ++half) {
        bf16x8 pf = *(const bf16x8*)(&sP[wave][lrow * 64 + (((half * 4 + lgrp) ^ (lrow & 7)) << 3)]);
#pragma unroll
        for (int dt = 0; dt < 4; ++dt) {
          const int d = dt * 16 + lrow;
          bf16x8 vf = *(const bf16x8*)(&sVt[buf][d * 64 + (((half * 4 + lgrp) ^ (d & 7)) << 3)]);
          accd[rt][dt] = __builtin_amdgcn_mfma_f32_16x16x32_bf16(pf, vf, accd[rt][dt], 0, 0, 0);
        }
      }
      __builtin_amdgcn_s_setprio(0);
    }
    buf ^= 1;
  }

  // epilogue: broadcast l from owner lanes, divide, store bf16
#pragma unroll
  for (int rt = 0; rt < 2; ++rt) {
#pragma unroll
    for (int j = 0; j < 4; ++j) {
      const float lv = __shfl(l_r[rt], lgrp * 4 + j, 64);
      const float inv = 1.f / lv;
      const int row = b * S_ + q0 + wave * 32 + rt * 16 + lgrp * 4 + j;
      __bf16* ob = o + (size_t)row * 1024 + h * 64;
#pragma unroll
      for (int dt = 0; dt < 4; ++dt) ob[dt * 16 + lrow] = (__bf16)(accd[rt][dt][j] * inv);
    }
  }
}

extern "C" void kernel_launch(void* const* d_in, const int* in_sizes, int n_in,
                              void* d_out, int out_size, void* d_ws, size_t ws_size,
                              hipStream_t stream) {
  (void)in_sizes; (void)n_in; (void)out_size; (void)ws_size;
  const float* x       = (const float*)d_in[0];
  const float* q_w     = (const float*)d_in[1];
  const float* q_b     = (const float*)d_in[2];
  const float* kv_w    = (const float*)d_in[3];
  const float* kv_b    = (const float*)d_in[4];
  const float* gamma_q = (const float*)d_in[5];
  const float* gamma_k = (const float*)d_in[6];
  const float* out_w   = (const float*)d_in[7];
  float* out = (float*)d_out;

  char* ws = (char*)d_ws;
  __bf16* x_bf   = (__bf16*)(ws);                  // 16 MB [8192,1024]
  __bf16* qkvw_bf = (__bf16*)(ws + (16ull << 20)); // 6 MB [3072,1024] (q_w then kv_w, contiguous)
  __bf16* ow_bf  = (__bf16*)(ws + (22ull << 20));  // 2 MB
  __bf16* q_bf   = (__bf16*)(ws + (24ull << 20));  // 16 MB [8192,1024] normalized q (log2-prescaled)
  __bf16* k_bf   = (__bf16*)(ws + (40ull << 20));  // 16 MB [8192,1024] normalized k
  __bf16* vt_bf  = (__bf16*)(ws + (56ull << 20));  // 16 MB [B,H,D,S]
  __bf16* at_bf  = (__bf16*)(ws + (72ull << 20));  // 16 MB [8192,1024]

  cvt_bf16<<<8192, 256, 0, stream>>>(x, x_bf);
  cvt_bf16<<<1024, 256, 0, stream>>>(q_w, qkvw_bf);                    // rows 0..1023
  cvt_bf16<<<2048, 256, 0, stream>>>(kv_w, qkvw_bf + (1024ull * 1024)); // rows 1024..3071
  cvt_bf16<<<1024, 256, 0, stream>>>(out_w, ow_bf);

  gemm_bt<4><<<dim3(24, 64), 256, 0, stream>>>(x_bf, qkvw_bf, q_b, kv_b, gamma_q, gamma_k,
                                               q_bf, k_bf, nullptr, vt_bf, 8192, 3072, 1024);

  attn_kernel<<<dim3(8, 64), 512, 0, stream>>>(q_bf, k_bf, vt_bf, at_bf);

  gemm_bt<1><<<dim3(8, 64), 256, 0, stream>>>(at_bf, ow_bf, nullptr, nullptr, nullptr, nullptr,
                                              nullptr, nullptr, out, nullptr, 8192, 1024, 1024);
}